// Round 4
// baseline (66.588 us; speedup 1.0000x reference)
//
#include <hip/hip_runtime.h>

#define NROWS 8192
#define DIM 128
#define NT 64                          // 8192 / 128 tiles per side
#define NPAIRBLK (NT * (NT + 1) / 2)   // 2080 upper-triangular tiles

typedef _Float16 f16x8 __attribute__((ext_vector_type(8)));
typedef _Float16 f16x2 __attribute__((ext_vector_type(2)));
typedef float f32x16 __attribute__((ext_vector_type(16)));

#define KHL2E 0.7213475204444817f   // log2(e)/2
#define L2E 1.4426950408889634f     // log2(e)

#define AS1(p) ((const __attribute__((address_space(1))) void*)(p))
#define AS3(p) ((__attribute__((address_space(3))) void*)(p))

// ---------------------------------------------------------------------------
// Kernel 1: per-row L2 normalize (fp32, as reference). 1024 threads = 16
// waves, one wave per row, 512 blocks. Emits zh (f16 normalized z1), sq
// (fp32 ||n1||^2), sposB (per-block partial sum of the positive term, 512
// floats), and re-zeroes the pairwise ticket counter (block 0)每 call.
// ---------------------------------------------------------------------------
__global__ __launch_bounds__(1024) void fmicl_normalize(
    const float* __restrict__ z1, const float* __restrict__ z2,
    float* __restrict__ sq, _Float16* __restrict__ zh,
    float* __restrict__ sposB, unsigned int* __restrict__ counter) {
  const int wid = threadIdx.x >> 6;
  const int lane = threadIdx.x & 63;
  const int row = blockIdx.x * 16 + wid;
  const float2 a = ((const float2*)(z1 + (size_t)row * DIM))[lane];
  const float2 b = ((const float2*)(z2 + (size_t)row * DIM))[lane];
  float s1 = a.x * a.x + a.y * a.y;
  float s2 = b.x * b.x + b.y * b.y;
#pragma unroll
  for (int off = 32; off; off >>= 1) {
    s1 += __shfl_xor(s1, off);
    s2 += __shfl_xor(s2, off);
  }
  const float inv1 = 1.0f / fmaxf(sqrtf(s1), 1e-12f);
  const float inv2 = 1.0f / fmaxf(sqrtf(s2), 1e-12f);
  const float n1x = a.x * inv1, n1y = a.y * inv1;
  const float n2x = b.x * inv2, n2y = b.y * inv2;
  float sqp = n1x * n1x + n1y * n1y;
  const float dx = n1x - n2x, dy = n1y - n2y;
  float dp = dx * dx + dy * dy;
#pragma unroll
  for (int off = 32; off; off >>= 1) {
    sqp += __shfl_xor(sqp, off);
    dp += __shfl_xor(dp, off);
  }
  f16x2 h;
  h.x = (_Float16)n1x;
  h.y = (_Float16)n1y;
  *(f16x2*)(zh + (size_t)row * DIM + 2 * lane) = h;
  __shared__ float sposL[16];
  if (lane == 0) {
    sq[row] = sqp;
    sposL[wid] = logf(expf(-0.5f * dp) + 1e-8f) + 1.0f;  // f'(g_pos)
  }
  __syncthreads();
  if (threadIdx.x == 0) {
    float s = 0.0f;
#pragma unroll
    for (int k = 0; k < 16; ++k) s += sposL[k];
    sposB[blockIdx.x] = s;
    if (blockIdx.x == 0) *counter = 0;  // reset ticket before pairwise runs
  }
}

// ---------------------------------------------------------------------------
// Kernel 2: fused Gram 128x128 tile + exp epilogue + last-block reduce.
// 1024 threads = 16 waves; each wave one 32x32 MFMA chain (8 x
// v_mfma_f32_32x32x16_f16 over K=128). LDS: one 64 KiB panel array
// (A rows [0,128), B rows [128,256), 256B/row) staged via global_load_lds
// width=16 with PRE-SWIZZLED global source (granule col ^= row&15); LDS dest
// stays linear, read side applies the same XOR -> conflict-minimal
// ds_read_b128 (each bank hit exactly 4x = b128 minimum).
// 2 blocks/CU x 16 waves = 32 waves/CU. Triangular 1D grid (2080 blocks),
// off-diagonal tiles weighted x2. Last-done block (fence/ticket/fence)
// reduces pairP + sposB and writes the scalar loss.
// ---------------------------------------------------------------------------
__global__ __launch_bounds__(1024, 8) void fmicl_pairwise(
    const _Float16* __restrict__ zh, const float* __restrict__ sq,
    float* __restrict__ pairP, const float* __restrict__ sposB,
    unsigned int* __restrict__ counter, float* __restrict__ out) {
  __shared__ _Float16 S[256 * DIM];  // 64 KiB: A rows 0..127, B rows 128..255
  __shared__ float wsum[16];
  __shared__ double red[32];
  __shared__ int amLast;

  const int tid = threadIdx.x;
  const int bid = blockIdx.x;

  // ---- triangular decode: row rt has (NT-rt) tiles; C(r) = r*NT - r(r-1)/2
  int rt = (int)(64.5f - sqrtf(64.5f * 64.5f - 2.0f * (float)bid));
  if (rt < 0) rt = 0;
  while (rt > 0 && (rt * NT - (rt * (rt - 1)) / 2) > bid) --rt;
  while (((rt + 1) * NT - ((rt + 1) * rt) / 2) <= bid) ++rt;
  const int ct = rt + (bid - (rt * NT - (rt * (rt - 1)) / 2));

  const int lane = tid & 63;
  const int wid = tid >> 6;
  const int i0 = rt << 7;
  const int j0 = ct << 7;

  // ---- stage 64 KiB via global_load_lds (linear LDS dest, swizzled src) ----
  // LDS[R][cs] holds global granule (R, cs ^ (R&15)); read uses the same XOR.
#pragma unroll
  for (int t = 0; t < 4; ++t) {
    const int P = t * 16 + wid;          // uniform per wave: 4-row group id
    const int R = P * 4 + (lane >> 4);   // combined row 0..255
    const int csrc = (lane & 15) ^ (R & 15);
    const _Float16* srow = (R < 128) ? zh + (size_t)(i0 + R) * DIM
                                     : zh + (size_t)(j0 + R - 128) * DIM;
    __builtin_amdgcn_global_load_lds(AS1(srow + csrc * 8), AS3(S + P * 512),
                                     16, 0, 0);
  }
  __syncthreads();

  // ---- one 32x32 chain per wave over K=128 ----
  const int l31 = lane & 31;
  const int lhi = lane >> 5;
  const int wm = (wid >> 2) * 32;  // wave sub-tile origin inside 128x128
  const int wn = (wid & 3) * 32;
  const uint4* S4 = (const uint4*)S;
  const int ra = wm + l31;
  const int rb = 128 + wn + l31;   // (rb&15) == ((wn+l31)&15) since 128%16==0
  f32x16 acc = {};
#pragma unroll
  for (int ks = 0; ks < 8; ++ks) {
    const int kg = ks * 2 + lhi;
    const uint4 va = S4[ra * 16 + (kg ^ (ra & 15))];
    const uint4 vb = S4[rb * 16 + (kg ^ (rb & 15))];
    acc = __builtin_amdgcn_mfma_f32_32x32x16_f16(
        __builtin_bit_cast(f16x8, va), __builtin_bit_cast(f16x8, vb), acc,
        0, 0, 0);
  }

  // ---- epilogue: g = exp2(log2e*dot - (K*si + K*sj)) == exp(-d2/2) ----
  // (clamp d2>=0 dropped: off-diag d2 ~= 2 - 2*dot with |dot|<~0.6; never <0)
  // C/D layout (32x32): col = lane&31, row = (reg&3)+8*(reg>>2)+4*(lane>>5)
  const int gj = j0 + wn + l31;
  const float ksj = KHL2E * sq[gj];
  float4 sqi[4];
#pragma unroll
  for (int q = 0; q < 4; ++q)
    sqi[q] = *(const float4*)&sq[i0 + wm + 4 * lhi + 8 * q];
  float gsum = 0.0f;
  const bool diagw = (rt == ct) && (wm == wn);  // wave-uniform
  if (diagw) {
#pragma unroll
    for (int r = 0; r < 16; ++r) {
      const float si = ((const float*)&sqi[r >> 2])[r & 3];
      const float c = fmaf(KHL2E, si, ksj);
      const float e = __builtin_amdgcn_exp2f(fmaf(L2E, acc[r], -c));
      const int mloc = (r & 3) + 4 * lhi + 8 * (r >> 2);
      gsum += (mloc != l31) ? e : 0.0f;  // mask true diagonal
    }
  } else {
#pragma unroll
    for (int r = 0; r < 16; ++r) {
      const float si = ((const float*)&sqi[r >> 2])[r & 3];
      const float c = fmaf(KHL2E, si, ksj);
      gsum += __builtin_amdgcn_exp2f(fmaf(L2E, acc[r], -c));
    }
  }
#pragma unroll
  for (int off = 32; off; off >>= 1) gsum += __shfl_xor(gsum, off);
  if (lane == 0) wsum[wid] = gsum;
  __syncthreads();
  if (tid == 0) {
    float s = 0.0f;
#pragma unroll
    for (int k = 0; k < 16; ++k) s += wsum[k];
    pairP[bid] = (rt == ct) ? s : 2.0f * s;  // mirrored off-diagonal tiles
    __threadfence();                          // release partial
    const unsigned int tkt = atomicAdd(counter, 1u);
    amLast = (tkt == NPAIRBLK - 1) ? 1 : 0;
  }
  __syncthreads();

  // ---- last-done block: fixed-order reduce (deterministic) + assemble ----
  if (amLast) {
    __threadfence();  // acquire all partials
    double nsum = (double)pairP[tid] + (double)pairP[tid + 1024];
    if (tid < NPAIRBLK - 2048) nsum += (double)pairP[tid + 2048];
    double psum = (tid < 512) ? (double)sposB[tid] : 0.0;
#pragma unroll
    for (int off = 32; off; off >>= 1) {
      nsum += __shfl_xor(nsum, off);
      psum += __shfl_xor(psum, off);
    }
    if (lane == 0) {
      red[wid] = nsum;
      red[16 + wid] = psum;
    }
    __syncthreads();
    if (tid == 0) {
      double n = 0.0, p = 0.0;
#pragma unroll
      for (int k = 0; k < 16; ++k) {
        n += red[k];
        p += red[16 + k];
      }
      const double pos_mean = p / (double)NROWS;
      // star_neg = g + EPS exactly, so star_mean = n/(N(N-1)) + EPS
      const double star_mean =
          n / ((double)NROWS * (double)(NROWS - 1)) + 1e-8;
      out[0] = (float)(-pos_mean + 1.5 * star_mean);
    }
  }
}

extern "C" void kernel_launch(void* const* d_in, const int* in_sizes, int n_in,
                              void* d_out, int out_size, void* d_ws,
                              size_t ws_size, hipStream_t stream) {
  const float* z1 = (const float*)d_in[0];
  const float* z2 = (const float*)d_in[1];
  float* out = (float*)d_out;
  char* ws = (char*)d_ws;

  // ws layout (every slot rewritten every call; counter reset by normalize):
  //   [0)      counter  uint          (pad to 64)
  //   [64)     pairP    float[2080]   (8320 B, pad to 8448)
  //   [8448)   sposB    float[512]    (2048 B)
  //   [10496)  sq       float[8192]   (32 KiB)
  //   [43264)  zh       f16[8192*128] (2 MiB, 16B-aligned)
  unsigned int* counter = (unsigned int*)ws;
  float* pairP = (float*)(ws + 64);
  float* sposB = (float*)(ws + 8448);
  float* sq = (float*)(ws + 10496);
  _Float16* zh = (_Float16*)(ws + 43264);

  fmicl_normalize<<<512, 1024, 0, stream>>>(z1, z2, sq, zh, sposB, counter);
  fmicl_pairwise<<<NPAIRBLK, 1024, 0, stream>>>(zh, sq, pairP, sposB, counter,
                                                out);
}

// Round 5
// 33.563 us; speedup vs baseline: 1.9840x; 1.9840x over previous
//
#include <hip/hip_runtime.h>

#define NROWS 8192
#define DIM 128
#define NT 32                          // 8192 / 256 tiles per side
#define NPAIRBLK (NT * (NT + 1) / 2)   // 528 upper-triangular tiles

typedef _Float16 f16x8 __attribute__((ext_vector_type(8)));
typedef _Float16 f16x2 __attribute__((ext_vector_type(2)));
typedef float f32x16 __attribute__((ext_vector_type(16)));

#define KHL2E 0.7213475204444817f   // log2(e)/2
#define L2E 1.4426950408889634f     // log2(e)

#define AS1(p) ((const __attribute__((address_space(1))) void*)(p))
#define AS3(p) ((__attribute__((address_space(3))) void*)(p))

// ---------------------------------------------------------------------------
// Kernel 1: per-row L2 normalize (fp32, as reference). 1024 threads = 16
// waves, one wave per row, 512 blocks. Emits zh (f16 normalized z1), sq
// (fp32 ||n1||^2), sposB (per-block partial sum of the positive term).
// No atomics anywhere.
// ---------------------------------------------------------------------------
__global__ __launch_bounds__(1024) void fmicl_normalize(
    const float* __restrict__ z1, const float* __restrict__ z2,
    float* __restrict__ sq, _Float16* __restrict__ zh,
    float* __restrict__ sposB) {
  const int wid = threadIdx.x >> 6;
  const int lane = threadIdx.x & 63;
  const int row = blockIdx.x * 16 + wid;
  const float2 a = ((const float2*)(z1 + (size_t)row * DIM))[lane];
  const float2 b = ((const float2*)(z2 + (size_t)row * DIM))[lane];
  float s1 = a.x * a.x + a.y * a.y;
  float s2 = b.x * b.x + b.y * b.y;
#pragma unroll
  for (int off = 32; off; off >>= 1) {
    s1 += __shfl_xor(s1, off);
    s2 += __shfl_xor(s2, off);
  }
  const float inv1 = 1.0f / fmaxf(sqrtf(s1), 1e-12f);
  const float inv2 = 1.0f / fmaxf(sqrtf(s2), 1e-12f);
  const float n1x = a.x * inv1, n1y = a.y * inv1;
  const float n2x = b.x * inv2, n2y = b.y * inv2;
  float sqp = n1x * n1x + n1y * n1y;
  const float dx = n1x - n2x, dy = n1y - n2y;
  float dp = dx * dx + dy * dy;
#pragma unroll
  for (int off = 32; off; off >>= 1) {
    sqp += __shfl_xor(sqp, off);
    dp += __shfl_xor(dp, off);
  }
  f16x2 h;
  h.x = (_Float16)n1x;
  h.y = (_Float16)n1y;
  *(f16x2*)(zh + (size_t)row * DIM + 2 * lane) = h;
  __shared__ float sposL[16];
  if (lane == 0) {
    sq[row] = sqp;
    sposL[wid] = logf(expf(-0.5f * dp) + 1e-8f) + 1.0f;  // f'(g_pos)
  }
  __syncthreads();
  if (threadIdx.x == 0) {
    float s = 0.0f;
#pragma unroll
    for (int k = 0; k < 16; ++k) s += sposL[k];
    sposB[blockIdx.x] = s;
  }
}

// ---------------------------------------------------------------------------
// Kernel 2: fused Gram 256x256 tile + exp epilogue. 1024 threads = 16 waves
// in a 4x4 grid; each wave owns a 64x64 output tile = 2x2 chains of
// v_mfma_f32_32x32x16_f16 over K=128 (4 ds_read_b128 + 4 MFMA per K-step:
// LDS-read:MFMA ratio 1.0). LDS: one 128 KiB panel array (A rows [0,256),
// B rows [256,512), 256 B/row) staged via global_load_lds width=16 with
// PRE-SWIZZLED global source (granule col ^= row&15); LDS dest linear, read
// side applies the same XOR (rule #21 involution pair) -> 0 bank conflicts
// (verified rounds 3/4). 1 block/CU, 528-block triangular grid, off-diagonal
// tiles weighted x2. Per-block partial to pairP; NO global atomics.
// ---------------------------------------------------------------------------
__global__ __launch_bounds__(1024, 4) void fmicl_pairwise(
    const _Float16* __restrict__ zh, const float* __restrict__ sq,
    float* __restrict__ pairP) {
  __shared__ _Float16 S[512 * DIM];  // 128 KiB: A rows 0..255, B rows 256..511
  __shared__ float wsum[16];

  const int tid = threadIdx.x;
  const int bid = blockIdx.x;

  // ---- triangular decode: C(r) = r*NT - r(r-1)/2 tiles before row r ----
  int rt = (int)(32.5f - sqrtf(32.5f * 32.5f - 2.0f * (float)bid));
  if (rt < 0) rt = 0;
  while (rt > 0 && (rt * NT - (rt * (rt - 1)) / 2) > bid) --rt;
  while (((rt + 1) * NT - ((rt + 1) * rt) / 2) <= bid) ++rt;
  const int ct = rt + (bid - (rt * NT - (rt * (rt - 1)) / 2));

  const int lane = tid & 63;
  const int wid = tid >> 6;
  const int i0 = rt << 8;
  const int j0 = ct << 8;

  // ---- stage 128 KiB via global_load_lds (linear LDS dest, swizzled src) ---
  // LDS[R][c] holds global granule (c ^ (R&15)); reads use the same XOR.
#pragma unroll
  for (int t = 0; t < 8; ++t) {
    const int P = t * 16 + wid;          // wave-uniform 4-row group id 0..127
    const int R = P * 4 + (lane >> 4);   // combined row 0..511
    const int csrc = (lane & 15) ^ (R & 15);
    const _Float16* srow = (R < 256) ? zh + (size_t)(i0 + R) * DIM
                                     : zh + (size_t)(j0 + R - 256) * DIM;
    __builtin_amdgcn_global_load_lds(AS1(srow + csrc * 8), AS3(S + P * 512),
                                     16, 0, 0);
  }
  __syncthreads();

  // ---- 2x2 chains of 32x32x16 per wave over K=128 ----
  const int l31 = lane & 31;
  const int lhi = lane >> 5;
  const int wm = (wid >> 2) * 64;  // wave tile origin inside 256x256
  const int wn = (wid & 3) * 64;
  const uint4* S4 = (const uint4*)S;
  const int ra0 = wm + l31;
  const int ra1 = wm + 32 + l31;
  const int rb0 = 256 + wn + l31;       // 256 % 16 == 0 keeps (r&15) intact
  const int rb1 = 256 + wn + 32 + l31;
  f32x16 acc00 = {}, acc01 = {}, acc10 = {}, acc11 = {};
#pragma unroll
  for (int ks = 0; ks < 8; ++ks) {
    const int kg = ks * 2 + lhi;
    const uint4 va0 = S4[ra0 * 16 + (kg ^ (ra0 & 15))];
    const uint4 va1 = S4[ra1 * 16 + (kg ^ (ra1 & 15))];
    const uint4 vb0 = S4[rb0 * 16 + (kg ^ (rb0 & 15))];
    const uint4 vb1 = S4[rb1 * 16 + (kg ^ (rb1 & 15))];
    const f16x8 a0 = __builtin_bit_cast(f16x8, va0);
    const f16x8 a1 = __builtin_bit_cast(f16x8, va1);
    const f16x8 b0 = __builtin_bit_cast(f16x8, vb0);
    const f16x8 b1 = __builtin_bit_cast(f16x8, vb1);
    acc00 = __builtin_amdgcn_mfma_f32_32x32x16_f16(a0, b0, acc00, 0, 0, 0);
    acc01 = __builtin_amdgcn_mfma_f32_32x32x16_f16(a0, b1, acc01, 0, 0, 0);
    acc10 = __builtin_amdgcn_mfma_f32_32x32x16_f16(a1, b0, acc10, 0, 0, 0);
    acc11 = __builtin_amdgcn_mfma_f32_32x32x16_f16(a1, b1, acc11, 0, 0, 0);
  }

  // ---- epilogue: g = exp2(log2e*dot - (K*si + K*sj)) == exp(-d2/2) ----
  // C/D layout (32x32): col = lane&31, row = (reg&3)+8*(reg>>2)+4*(lane>>5)
  const float ksj0 = KHL2E * sq[j0 + wn + l31];
  const float ksj1 = KHL2E * sq[j0 + wn + 32 + l31];
  float gsum = 0.0f;
#pragma unroll
  for (int mi = 0; mi < 2; ++mi) {
    const int mbase = wm + mi * 32;
    float4 sqi[4];
#pragma unroll
    for (int q = 0; q < 4; ++q)
      sqi[q] = *(const float4*)&sq[i0 + mbase + 4 * lhi + 8 * q];
#pragma unroll
    for (int ni = 0; ni < 2; ++ni) {
      const f32x16& acc = (mi == 0) ? (ni == 0 ? acc00 : acc01)
                                    : (ni == 0 ? acc10 : acc11);
      const float ksj = ni ? ksj1 : ksj0;
      const bool diagsub = (rt == ct) && (mbase == wn + ni * 32);  // uniform
      if (diagsub) {
#pragma unroll
        for (int r = 0; r < 16; ++r) {
          const float si = ((const float*)&sqi[r >> 2])[r & 3];
          const float c = fmaf(KHL2E, si, ksj);
          const float e = __builtin_amdgcn_exp2f(fmaf(L2E, acc[r], -c));
          const int mloc = (r & 3) + 4 * lhi + 8 * (r >> 2);
          gsum += (mloc != l31) ? e : 0.0f;  // mask true diagonal
        }
      } else {
#pragma unroll
        for (int r = 0; r < 16; ++r) {
          const float si = ((const float*)&sqi[r >> 2])[r & 3];
          const float c = fmaf(KHL2E, si, ksj);
          gsum += __builtin_amdgcn_exp2f(fmaf(L2E, acc[r], -c));
        }
      }
    }
  }
#pragma unroll
  for (int off = 32; off; off >>= 1) gsum += __shfl_xor(gsum, off);
  if (lane == 0) wsum[wid] = gsum;
  __syncthreads();
  if (tid == 0) {
    float s = 0.0f;
#pragma unroll
    for (int k = 0; k < 16; ++k) s += wsum[k];
    pairP[bid] = (rt == ct) ? s : 2.0f * s;  // mirrored off-diagonal tiles
  }
}

// ---------------------------------------------------------------------------
// Kernel 3: single-block fused reduce + assemble scalar (deterministic
// fixed-order tree). star_neg = g + EPS exactly, so
// star_mean = negSum/(N(N-1)) + EPS.
// ---------------------------------------------------------------------------
__global__ void fmicl_reduce(const float* __restrict__ pairP,
                             const float* __restrict__ sposB,
                             float* __restrict__ out) {
  const int t = threadIdx.x;  // 1024 threads = 16 waves
  double nsum = (t < NPAIRBLK) ? (double)pairP[t] : 0.0;
  double psum = (t < 512) ? (double)sposB[t] : 0.0;
#pragma unroll
  for (int off = 32; off; off >>= 1) {
    nsum += __shfl_xor(nsum, off);
    psum += __shfl_xor(psum, off);
  }
  __shared__ double ls[2][16];
  const int lane = t & 63;
  const int wid = t >> 6;
  if (lane == 0) {
    ls[0][wid] = nsum;
    ls[1][wid] = psum;
  }
  __syncthreads();
  if (t == 0) {
    double n = 0.0, p = 0.0;
#pragma unroll
    for (int k = 0; k < 16; ++k) {
      n += ls[0][k];
      p += ls[1][k];
    }
    const double pos_mean = p / (double)NROWS;
    const double star_mean = n / ((double)NROWS * (double)(NROWS - 1)) + 1e-8;
    out[0] = (float)(-pos_mean + 1.5 * star_mean);
  }
}

extern "C" void kernel_launch(void* const* d_in, const int* in_sizes, int n_in,
                              void* d_out, int out_size, void* d_ws,
                              size_t ws_size, hipStream_t stream) {
  const float* z1 = (const float*)d_in[0];
  const float* z2 = (const float*)d_in[1];
  float* out = (float*)d_out;
  char* ws = (char*)d_ws;

  // ws layout (every slot rewritten every call; no memset needed):
  //   [0)      pairP float[528]   (pad to 4096)
  //   [4096)   sposB float[512]   (2048 B)
  //   [6144)   sq    float[8192]  (32 KiB)
  //   [38912)  zh    f16[8192*128] (2 MiB, 16B-aligned)
  float* pairP = (float*)(ws + 0);
  float* sposB = (float*)(ws + 4096);
  float* sq = (float*)(ws + 6144);
  _Float16* zh = (_Float16*)(ws + 38912);

  fmicl_normalize<<<512, 1024, 0, stream>>>(z1, z2, sq, zh, sposB);
  fmicl_pairwise<<<NPAIRBLK, 1024, 0, stream>>>(zh, sq, pairP);
  fmicl_reduce<<<1, 1024, 0, stream>>>(pairP, sposB, out);
}

// Round 6
// 30.949 us; speedup vs baseline: 2.1516x; 1.0845x over previous
//
#include <hip/hip_runtime.h>

#define NROWS 8192
#define DIM 128
#define NT 32                          // 8192 / 256 tiles per side
#define NPAIRBLK (NT * (NT + 1) / 2)   // 528 upper-triangular tiles

typedef _Float16 f16x8 __attribute__((ext_vector_type(8)));
typedef _Float16 f16x2 __attribute__((ext_vector_type(2)));
typedef float f32x16 __attribute__((ext_vector_type(16)));

#define L2E 1.4426950408889634f     // log2(e)

#define AS1(p) ((const __attribute__((address_space(1))) void*)(p))
#define AS3(p) ((__attribute__((address_space(3))) void*)(p))

// ---------------------------------------------------------------------------
// Kernel 1: per-row L2 normalize (fp32, as reference). 1024 threads = 16
// waves, one wave per row, 512 blocks. Emits zh (f16 normalized z1) and
// sposB (per-block partial sum of the positive term). sq is NOT needed:
// ||n1||^2 = 1 +- 3e-7 by construction, absorbed into the epilogue constant.
// ---------------------------------------------------------------------------
__global__ __launch_bounds__(1024) void fmicl_normalize(
    const float* __restrict__ z1, const float* __restrict__ z2,
    _Float16* __restrict__ zh, float* __restrict__ sposB) {
  const int wid = threadIdx.x >> 6;
  const int lane = threadIdx.x & 63;
  const int row = blockIdx.x * 16 + wid;
  const float2 a = ((const float2*)(z1 + (size_t)row * DIM))[lane];
  const float2 b = ((const float2*)(z2 + (size_t)row * DIM))[lane];
  float s1 = a.x * a.x + a.y * a.y;
  float s2 = b.x * b.x + b.y * b.y;
#pragma unroll
  for (int off = 32; off; off >>= 1) {
    s1 += __shfl_xor(s1, off);
    s2 += __shfl_xor(s2, off);
  }
  const float inv1 = 1.0f / fmaxf(sqrtf(s1), 1e-12f);
  const float inv2 = 1.0f / fmaxf(sqrtf(s2), 1e-12f);
  const float n1x = a.x * inv1, n1y = a.y * inv1;
  const float n2x = b.x * inv2, n2y = b.y * inv2;
  const float dx = n1x - n2x, dy = n1y - n2y;
  float dp = dx * dx + dy * dy;
#pragma unroll
  for (int off = 32; off; off >>= 1) dp += __shfl_xor(dp, off);
  f16x2 h;
  h.x = (_Float16)n1x;
  h.y = (_Float16)n1y;
  *(f16x2*)(zh + (size_t)row * DIM + 2 * lane) = h;
  __shared__ float sposL[16];
  if (lane == 0)
    sposL[wid] = logf(expf(-0.5f * dp) + 1e-8f) + 1.0f;  // f'(g_pos)
  __syncthreads();
  if (threadIdx.x == 0) {
    float s = 0.0f;
#pragma unroll
    for (int k = 0; k < 16; ++k) s += sposL[k];
    sposB[blockIdx.x] = s;
  }
}

// ---------------------------------------------------------------------------
// Kernel 2: fused Gram 256x256 tile + exp epilogue. 1024 threads = 16 waves
// (4x4); each wave owns a 64x64 output tile = 2x2 chains of
// v_mfma_f32_32x32x16_f16 over K=128. LDS: one 128 KiB panel array (A rows
// [0,256), B rows [256,512), 256 B/row) staged via global_load_lds width=16
// with PRE-SWIZZLED global source (granule col ^= row&15); LDS dest linear,
// read side applies the same XOR (rule #21 involution pair) -> 0 bank
// conflicts (verified rounds 3-5). Epilogue per pair is 3 ops:
// g = exp2(fma(log2e, dot, -log2e)) == exp(dot - 1) == exp(-d2/2) for
// unit-norm rows (si=sj=1 +- 3e-7; error << fp16-dot error, absmax 0.0).
// Triangular 1D grid (528 blocks), off-diagonal tiles weighted x2.
// Per-block partial to pairP; NO global atomics.
// ---------------------------------------------------------------------------
__global__ __launch_bounds__(1024, 4) void fmicl_pairwise(
    const _Float16* __restrict__ zh, float* __restrict__ pairP) {
  __shared__ _Float16 S[512 * DIM];  // 128 KiB: A rows 0..255, B rows 256..511
  __shared__ float wsum[16];

  const int tid = threadIdx.x;
  const int bid = blockIdx.x;

  // ---- triangular decode: C(r) = r*NT - r(r-1)/2 tiles before row r ----
  int rt = (int)(32.5f - sqrtf(32.5f * 32.5f - 2.0f * (float)bid));
  if (rt < 0) rt = 0;
  while (rt > 0 && (rt * NT - (rt * (rt - 1)) / 2) > bid) --rt;
  while (((rt + 1) * NT - ((rt + 1) * rt) / 2) <= bid) ++rt;
  const int ct = rt + (bid - (rt * NT - (rt * (rt - 1)) / 2));

  const int lane = tid & 63;
  const int wid = tid >> 6;
  const int i0 = rt << 8;
  const int j0 = ct << 8;

  // ---- stage 128 KiB via global_load_lds (linear LDS dest, swizzled src) ---
  // LDS[R][c] holds global granule (c ^ (R&15)); reads use the same XOR.
#pragma unroll
  for (int t = 0; t < 8; ++t) {
    const int P = t * 16 + wid;          // wave-uniform 4-row group id 0..127
    const int R = P * 4 + (lane >> 4);   // combined row 0..511
    const int csrc = (lane & 15) ^ (R & 15);
    const _Float16* srow = (R < 256) ? zh + (size_t)(i0 + R) * DIM
                                     : zh + (size_t)(j0 + R - 256) * DIM;
    __builtin_amdgcn_global_load_lds(AS1(srow + csrc * 8), AS3(S + P * 512),
                                     16, 0, 0);
  }
  __syncthreads();

  // ---- 2x2 chains of 32x32x16 per wave over K=128 ----
  const int l31 = lane & 31;
  const int lhi = lane >> 5;
  const int wm = (wid >> 2) * 64;  // wave tile origin inside 256x256
  const int wn = (wid & 3) * 64;
  const uint4* S4 = (const uint4*)S;
  const int ra0 = wm + l31;
  const int ra1 = wm + 32 + l31;
  const int rb0 = 256 + wn + l31;       // 256 % 16 == 0 keeps (r&15) intact
  const int rb1 = 256 + wn + 32 + l31;
  f32x16 acc00 = {}, acc01 = {}, acc10 = {}, acc11 = {};
#pragma unroll
  for (int ks = 0; ks < 8; ++ks) {
    const int kg = ks * 2 + lhi;
    const uint4 va0 = S4[ra0 * 16 + (kg ^ (ra0 & 15))];
    const uint4 va1 = S4[ra1 * 16 + (kg ^ (ra1 & 15))];
    const uint4 vb0 = S4[rb0 * 16 + (kg ^ (rb0 & 15))];
    const uint4 vb1 = S4[rb1 * 16 + (kg ^ (rb1 & 15))];
    const f16x8 a0 = __builtin_bit_cast(f16x8, va0);
    const f16x8 a1 = __builtin_bit_cast(f16x8, va1);
    const f16x8 b0 = __builtin_bit_cast(f16x8, vb0);
    const f16x8 b1 = __builtin_bit_cast(f16x8, vb1);
    acc00 = __builtin_amdgcn_mfma_f32_32x32x16_f16(a0, b0, acc00, 0, 0, 0);
    acc01 = __builtin_amdgcn_mfma_f32_32x32x16_f16(a0, b1, acc01, 0, 0, 0);
    acc10 = __builtin_amdgcn_mfma_f32_32x32x16_f16(a1, b0, acc10, 0, 0, 0);
    acc11 = __builtin_amdgcn_mfma_f32_32x32x16_f16(a1, b1, acc11, 0, 0, 0);
  }

  // ---- epilogue: g = exp2(log2e*dot - log2e) == exp(dot-1) == exp(-d2/2) ---
  // C/D layout (32x32): col = lane&31, row = (reg&3)+8*(reg>>2)+4*(lane>>5)
  float gsum = 0.0f;
#pragma unroll
  for (int mi = 0; mi < 2; ++mi) {
#pragma unroll
    for (int ni = 0; ni < 2; ++ni) {
      const f32x16& acc = (mi == 0) ? (ni == 0 ? acc00 : acc01)
                                    : (ni == 0 ? acc10 : acc11);
      const bool diagsub =
          (rt == ct) && (wm + mi * 32 == wn + ni * 32);  // wave-uniform
      if (diagsub) {
#pragma unroll
        for (int r = 0; r < 16; ++r) {
          const float e =
              __builtin_amdgcn_exp2f(fmaf(L2E, acc[r], -L2E));
          const int mloc = (r & 3) + 4 * lhi + 8 * (r >> 2);
          gsum += (mloc != l31) ? e : 0.0f;  // mask true diagonal
        }
      } else {
#pragma unroll
        for (int r = 0; r < 16; ++r)
          gsum += __builtin_amdgcn_exp2f(fmaf(L2E, acc[r], -L2E));
      }
    }
  }
#pragma unroll
  for (int off = 32; off; off >>= 1) gsum += __shfl_xor(gsum, off);
  if (lane == 0) wsum[wid] = gsum;
  __syncthreads();
  if (tid == 0) {
    float s = 0.0f;
#pragma unroll
    for (int k = 0; k < 16; ++k) s += wsum[k];
    pairP[bid] = (rt == ct) ? s : 2.0f * s;  // mirrored off-diagonal tiles
  }
}

// ---------------------------------------------------------------------------
// Kernel 3: single-block fused reduce + assemble scalar (deterministic
// fixed-order tree). star_neg = g + EPS exactly, so
// star_mean = negSum/(N(N-1)) + EPS.
// ---------------------------------------------------------------------------
__global__ void fmicl_reduce(const float* __restrict__ pairP,
                             const float* __restrict__ sposB,
                             float* __restrict__ out) {
  const int t = threadIdx.x;  // 1024 threads = 16 waves
  double nsum = (t < NPAIRBLK) ? (double)pairP[t] : 0.0;
  double psum = (t < 512) ? (double)sposB[t] : 0.0;
#pragma unroll
  for (int off = 32; off; off >>= 1) {
    nsum += __shfl_xor(nsum, off);
    psum += __shfl_xor(psum, off);
  }
  __shared__ double ls[2][16];
  const int lane = t & 63;
  const int wid = t >> 6;
  if (lane == 0) {
    ls[0][wid] = nsum;
    ls[1][wid] = psum;
  }
  __syncthreads();
  if (t == 0) {
    double n = 0.0, p = 0.0;
#pragma unroll
    for (int k = 0; k < 16; ++k) {
      n += ls[0][k];
      p += ls[1][k];
    }
    const double pos_mean = p / (double)NROWS;
    const double star_mean = n / ((double)NROWS * (double)(NROWS - 1)) + 1e-8;
    out[0] = (float)(-pos_mean + 1.5 * star_mean);
  }
}

extern "C" void kernel_launch(void* const* d_in, const int* in_sizes, int n_in,
                              void* d_out, int out_size, void* d_ws,
                              size_t ws_size, hipStream_t stream) {
  const float* z1 = (const float*)d_in[0];
  const float* z2 = (const float*)d_in[1];
  float* out = (float*)d_out;
  char* ws = (char*)d_ws;

  // ws layout (every slot rewritten every call; no memset needed):
  //   [0)     pairP float[528]    (pad to 4096)
  //   [4096)  sposB float[512]    (2048 B)
  //   [6144)  zh    f16[8192*128] (2 MiB, 16B-aligned)
  float* pairP = (float*)(ws + 0);
  float* sposB = (float*)(ws + 4096);
  _Float16* zh = (_Float16*)(ws + 6144);

  fmicl_normalize<<<512, 1024, 0, stream>>>(z1, z2, zh, sposB);
  fmicl_pairwise<<<NPAIRBLK, 1024, 0, stream>>>(zh, pairP);
  fmicl_reduce<<<1, 1024, 0, stream>>>(pairP, sposB, out);
}

// Round 7
// 30.127 us; speedup vs baseline: 2.2103x; 1.0273x over previous
//
#include <hip/hip_runtime.h>

#define NROWS 8192
#define DIM 128
#define NT 64                          // 8192 / 128 tiles per side
#define NPAIRBLK (NT * (NT + 1) / 2)   // 2080 upper-triangular tiles

typedef _Float16 f16x8 __attribute__((ext_vector_type(8)));
typedef _Float16 f16x2 __attribute__((ext_vector_type(2)));
typedef float f32x16 __attribute__((ext_vector_type(16)));

#define L2E 1.4426950408889634f     // log2(e)

#define AS1(p) ((const __attribute__((address_space(1))) void*)(p))
#define AS3(p) ((__attribute__((address_space(3))) void*)(p))

// ---------------------------------------------------------------------------
// Kernel 1: per-row L2 normalize (fp32, as reference). 1024 threads = 16
// waves, one wave per row, 512 blocks. Emits zh (f16 normalized z1) and
// sposB (per-block partial of the positive term). ||n1||^2 = 1 +- 3e-7 by
// construction -> absorbed into the epilogue constant (round-6 verified).
// ---------------------------------------------------------------------------
__global__ __launch_bounds__(1024) void fmicl_normalize(
    const float* __restrict__ z1, const float* __restrict__ z2,
    _Float16* __restrict__ zh, float* __restrict__ sposB) {
  const int wid = threadIdx.x >> 6;
  const int lane = threadIdx.x & 63;
  const int row = blockIdx.x * 16 + wid;
  const float2 a = ((const float2*)(z1 + (size_t)row * DIM))[lane];
  const float2 b = ((const float2*)(z2 + (size_t)row * DIM))[lane];
  float s1 = a.x * a.x + a.y * a.y;
  float s2 = b.x * b.x + b.y * b.y;
#pragma unroll
  for (int off = 32; off; off >>= 1) {
    s1 += __shfl_xor(s1, off);
    s2 += __shfl_xor(s2, off);
  }
  const float inv1 = 1.0f / fmaxf(sqrtf(s1), 1e-12f);
  const float inv2 = 1.0f / fmaxf(sqrtf(s2), 1e-12f);
  const float n1x = a.x * inv1, n1y = a.y * inv1;
  const float n2x = b.x * inv2, n2y = b.y * inv2;
  const float dx = n1x - n2x, dy = n1y - n2y;
  float dp = dx * dx + dy * dy;
#pragma unroll
  for (int off = 32; off; off >>= 1) dp += __shfl_xor(dp, off);
  f16x2 h;
  h.x = (_Float16)n1x;
  h.y = (_Float16)n1y;
  *(f16x2*)(zh + (size_t)row * DIM + 2 * lane) = h;
  __shared__ float sposL[16];
  if (lane == 0)
    sposL[wid] = logf(expf(-0.5f * dp) + 1e-8f) + 1.0f;  // f'(g_pos)
  __syncthreads();
  if (threadIdx.x == 0) {
    float s = 0.0f;
#pragma unroll
    for (int k = 0; k < 16; ++k) s += sposL[k];
    sposB[blockIdx.x] = s;
  }
}

// ---------------------------------------------------------------------------
// Kernel 2: fused Gram 128x128 tile + exp epilogue. 512 threads = 8 waves
// (4 M x 2 N); each wave owns 32x64 = 2 chains of v_mfma_f32_32x32x16_f16
// sharing the A fragment (3 ds_read_b128 + 2 MFMA per K-step). LDS 64 KiB
// (A rows [0,128), B rows [128,256), 256 B/row) -> 2 CONCURRENT blocks/CU:
// one block's MFMA/epilogue overlaps the other's staging, and the 2080-block
// grid (4.06 rounds of 512 resident) amortizes ramp/tail (vs 2.06 rounds of
// 256 at 128-KiB LDS). Staging via global_load_lds width=16 with
// PRE-SWIZZLED global source (granule col ^= row&15); LDS dest linear, read
// side same XOR (involution pair; rounds 3-6 verified, 0 bank conflicts).
// Epilogue: g = exp2(fma(log2e, dot, -log2e)) == exp(-d2/2) for unit rows.
// XCD-chunked tile swizzle: 2080 % 8 == 0, tile = (bid&7)*260 + bid>>3 ->
// each XCD owns 260 consecutive triangular tiles -> A-panels L2-resident.
// No atomics.
// ---------------------------------------------------------------------------
__global__ __launch_bounds__(512, 4) void fmicl_pairwise(
    const _Float16* __restrict__ zh, float* __restrict__ pairP) {
  __shared__ _Float16 S[256 * DIM];  // 64 KiB: A rows 0..127, B rows 128..255
  __shared__ float wsum[8];

  const int tid = threadIdx.x;
  // XCD-chunked swizzle (bijective: 2080 = 8 * 260)
  const int tile = (blockIdx.x & 7) * (NPAIRBLK / 8) + (blockIdx.x >> 3);

  // ---- triangular decode: C(r) = r*NT - r(r-1)/2 tiles before row r ----
  int rt = (int)(64.5f - sqrtf(64.5f * 64.5f - 2.0f * (float)tile));
  if (rt < 0) rt = 0;
  while (rt > 0 && (rt * NT - (rt * (rt - 1)) / 2) > tile) --rt;
  while (((rt + 1) * NT - ((rt + 1) * rt) / 2) <= tile) ++rt;
  const int ct = rt + (tile - (rt * NT - (rt * (rt - 1)) / 2));

  const int lane = tid & 63;
  const int wid = tid >> 6;
  const int i0 = rt << 7;
  const int j0 = ct << 7;

  // ---- stage 64 KiB via global_load_lds (linear LDS dest, swizzled src) ----
  // LDS[R][c] holds global granule (c ^ (R&15)); reads use the same XOR.
#pragma unroll
  for (int t = 0; t < 8; ++t) {
    const int P = t * 8 + wid;           // wave-uniform 4-row group id 0..63
    const int R = P * 4 + (lane >> 4);   // combined row 0..255
    const int csrc = (lane & 15) ^ (R & 15);
    const _Float16* srow = (R < 128) ? zh + (size_t)(i0 + R) * DIM
                                     : zh + (size_t)(j0 + R - 128) * DIM;
    __builtin_amdgcn_global_load_lds(AS1(srow + csrc * 8), AS3(S + P * 512),
                                     16, 0, 0);
  }
  __syncthreads();

  // ---- 2 chains of 32x32x16 per wave (shared A frag) over K=128 ----
  const int l31 = lane & 31;
  const int lhi = lane >> 5;
  const int wm = (wid >> 1) * 32;  // wave tile origin inside 128x128
  const int wn = (wid & 1) * 64;
  const uint4* S4 = (const uint4*)S;
  const int ra = wm + l31;
  const int rb0 = 128 + wn + l31;       // 128 % 16 == 0 keeps (r&15) intact
  const int rb1 = 128 + wn + 32 + l31;
  f32x16 acc0 = {}, acc1 = {};
#pragma unroll
  for (int ks = 0; ks < 8; ++ks) {
    const int kg = ks * 2 + lhi;
    const uint4 va = S4[ra * 16 + (kg ^ (ra & 15))];
    const uint4 vb0 = S4[rb0 * 16 + (kg ^ (rb0 & 15))];
    const uint4 vb1 = S4[rb1 * 16 + (kg ^ (rb1 & 15))];
    const f16x8 af = __builtin_bit_cast(f16x8, va);
    acc0 = __builtin_amdgcn_mfma_f32_32x32x16_f16(
        af, __builtin_bit_cast(f16x8, vb0), acc0, 0, 0, 0);
    acc1 = __builtin_amdgcn_mfma_f32_32x32x16_f16(
        af, __builtin_bit_cast(f16x8, vb1), acc1, 0, 0, 0);
  }

  // ---- epilogue: g = exp2(log2e*dot - log2e) == exp(dot-1) == exp(-d2/2) ---
  // C/D layout (32x32): col = lane&31, row = (reg&3)+8*(reg>>2)+4*(lane>>5)
  float gsum = 0.0f;
#pragma unroll
  for (int ni = 0; ni < 2; ++ni) {
    const f32x16& acc = ni ? acc1 : acc0;
    const bool diagsub = (rt == ct) && (wm == wn + ni * 32);  // wave-uniform
    if (diagsub) {
#pragma unroll
      for (int r = 0; r < 16; ++r) {
        const float e = __builtin_amdgcn_exp2f(fmaf(L2E, acc[r], -L2E));
        const int mloc = (r & 3) + 4 * lhi + 8 * (r >> 2);
        gsum += (mloc != l31) ? e : 0.0f;  // mask true diagonal
      }
    } else {
#pragma unroll
      for (int r = 0; r < 16; ++r)
        gsum += __builtin_amdgcn_exp2f(fmaf(L2E, acc[r], -L2E));
    }
  }
#pragma unroll
  for (int off = 32; off; off >>= 1) gsum += __shfl_xor(gsum, off);
  if (lane == 0) wsum[wid] = gsum;
  __syncthreads();
  if (tid == 0) {
    float s = 0.0f;
#pragma unroll
    for (int k = 0; k < 8; ++k) s += wsum[k];
    pairP[tile] = (rt == ct) ? s : 2.0f * s;  // mirrored off-diagonal tiles
  }
}

// ---------------------------------------------------------------------------
// Kernel 3: single-block fused reduce + assemble scalar (deterministic
// fixed-order tree). star_neg = g + EPS exactly, so
// star_mean = negSum/(N(N-1)) + EPS.
// ---------------------------------------------------------------------------
__global__ void fmicl_reduce(const float* __restrict__ pairP,
                             const float* __restrict__ sposB,
                             float* __restrict__ out) {
  const int t = threadIdx.x;  // 1024 threads = 16 waves
  double nsum = (double)pairP[t] + (double)pairP[t + 1024];
  if (t < NPAIRBLK - 2048) nsum += (double)pairP[t + 2048];
  double psum = (t < 512) ? (double)sposB[t] : 0.0;
#pragma unroll
  for (int off = 32; off; off >>= 1) {
    nsum += __shfl_xor(nsum, off);
    psum += __shfl_xor(psum, off);
  }
  __shared__ double ls[2][16];
  const int lane = t & 63;
  const int wid = t >> 6;
  if (lane == 0) {
    ls[0][wid] = nsum;
    ls[1][wid] = psum;
  }
  __syncthreads();
  if (t == 0) {
    double n = 0.0, p = 0.0;
#pragma unroll
    for (int k = 0; k < 16; ++k) {
      n += ls[0][k];
      p += ls[1][k];
    }
    const double pos_mean = p / (double)NROWS;
    const double star_mean = n / ((double)NROWS * (double)(NROWS - 1)) + 1e-8;
    out[0] = (float)(-pos_mean + 1.5 * star_mean);
  }
}

extern "C" void kernel_launch(void* const* d_in, const int* in_sizes, int n_in,
                              void* d_out, int out_size, void* d_ws,
                              size_t ws_size, hipStream_t stream) {
  const float* z1 = (const float*)d_in[0];
  const float* z2 = (const float*)d_in[1];
  float* out = (float*)d_out;
  char* ws = (char*)d_ws;

  // ws layout (every slot rewritten every call; no memset needed):
  //   [0)      pairP float[2080]   (8320 B, pad to 8448)
  //   [8448)   sposB float[512]    (2048 B)
  //   [10496)  zh    f16[8192*128] (2 MiB, 16B-aligned)
  float* pairP = (float*)(ws + 0);
  float* sposB = (float*)(ws + 8448);
  _Float16* zh = (_Float16*)(ws + 10496);

  fmicl_normalize<<<512, 1024, 0, stream>>>(z1, z2, zh, sposB);
  fmicl_pairwise<<<NPAIRBLK, 512, 0, stream>>>(zh, pairP);
  fmicl_reduce<<<1, 1024, 0, stream>>>(pairP, sposB, out);
}